// Round 9
// baseline (590.017 us; speedup 1.0000x reference)
//
#include <hip/hip_runtime.h>

typedef unsigned short ushort_t;
typedef __attribute__((ext_vector_type(8))) short short8;
typedef __attribute__((ext_vector_type(4))) float f32x4;

#define B_ 2
#define HW_ 65536          // 256*256 per batch
#define MTOT_ 131072       // B*H*W rows
#define C_ 192
#define C3_ 576
#define HEADS_ 4
#define CH_ 48

// ---- workspace layout (bytes), total ~302.5 MB ----
#define OFF_QKV0  ((size_t)0)                       // bf16 131072*576*2 = 150,994,944
#define OFF_QKV1  ((size_t)150994944)               // bf16, same size
#define OFF_P     OFF_QKV0                          // gram partials (15.7 MB) alias qkv0: dead after dwconv
#define OFF_BT    ((size_t)301989888)               // w_qkv^T bf16 576*192*2 = 221,184
#define OFF_S     ((size_t)302211072)               // fp32 8*48*48 = 73,728 B
#define OFF_NQ    ((size_t)302284800)               // fp32 8*48 = 1,536 B
#define OFF_NK    ((size_t)302286336)               // fp32 8*48 = 1,536 B
#define OFF_ATTN  ((size_t)302287872)               // fp32 8*48*48 = 73,728 B
#define OFF_MT    ((size_t)302361600)               // bf16 2*192*192 = 147,456 B

__device__ __forceinline__ float b2f(ushort_t u) {
    unsigned v = ((unsigned)u) << 16;
    return __builtin_bit_cast(float, v);
}
__device__ __forceinline__ ushort_t f2b(float f) {
    unsigned u = __builtin_bit_cast(unsigned, f);
    u = (u + 0x7fffu + ((u >> 16) & 1u)) >> 16;   // RNE
    return (ushort_t)u;
}
__device__ __forceinline__ void storev(float* p, float v) { *p = v; }
__device__ __forceinline__ void storev(ushort_t* p, float v) { *p = f2b(v); }

// ---- register staging for the GEMM software pipeline ----
// A-row fragment kept RAW in registers; conversion (fp32 path) happens at the
// LDS-write site so the vmcnt wait lands after the previous MFMA phase.
struct ARegU { uint4 lo, hi; };
struct ARegF { float4 a, b, c, d; };
template <typename AT> struct ARegT;
template <> struct ARegT<ushort_t> { using T = ARegU; };
template <> struct ARegT<float>    { using T = ARegF; };

__device__ __forceinline__ void aload(ARegU& r, const ushort_t* p) {
    r.lo = *(const uint4*)p; r.hi = *(const uint4*)(p + 8);
}
__device__ __forceinline__ void aload(ARegF& r, const float* p) {
    r.a = *(const float4*)p;       r.b = *(const float4*)(p + 4);
    r.c = *(const float4*)(p + 8); r.d = *(const float4*)(p + 12);
}
__device__ __forceinline__ void awrite(const ARegU& r, ushort_t* l) {
    *(uint4*)l = r.lo; *(uint4*)(l + 8) = r.hi;
}
__device__ __forceinline__ void awrite(const ARegF& r, ushort_t* l) {
    ushort_t o[16];
    o[0]=f2b(r.a.x); o[1]=f2b(r.a.y); o[2]=f2b(r.a.z); o[3]=f2b(r.a.w);
    o[4]=f2b(r.b.x); o[5]=f2b(r.b.y); o[6]=f2b(r.b.z); o[7]=f2b(r.b.w);
    o[8]=f2b(r.c.x); o[9]=f2b(r.c.y); o[10]=f2b(r.c.z); o[11]=f2b(r.c.w);
    o[12]=f2b(r.d.x); o[13]=f2b(r.d.y); o[14]=f2b(r.d.z); o[15]=f2b(r.d.w);
    *(uint4*)l = *(uint4*)o; *(uint4*)(l + 8) = *(uint4*)(o + 8);
}

// K0: transpose+convert w_qkv fp32 [192,576] -> bf16 [576,192]
__global__ void k0_transpose(const float* __restrict__ w, ushort_t* __restrict__ bt) {
    int idx = blockIdx.x * 256 + threadIdx.x;        // 576*192 = 110592 exactly
    int n = idx / 192, k = idx - n * 192;
    bt[idx] = f2b(w[k * 576 + n]);
}

// MFMA GEMM: C[M,N] = A[M,192] * BT[N,192]^T(bf16) + bias(fp32).  A fp32 (converted
// during LDS write) or bf16.  64x192 C supertile/block (3 n-tiles), BK=64.
// ROUND-9: register-staged software pipeline.  Round-8 profile: 117us with
// MfmaUtil 10 / VALU 17 / HBM 21% / occ 30% — exposed global-load latency
// (loads for iter k issued only after MFMA of k-1 fully drained).  New loop:
//   prologue: load k=0 -> regs
//   iter k:  [barrier] regs->LDS  [barrier]  issue loads k+1 -> regs ; MFMA(k)
// The vmcnt wait moves to the next LDS-write, i.e. AFTER 24 MFMAs, hiding HBM
// latency inside the compute phase (same pattern as k3_gram_mfma).
// LDS-transposed wide epilogue (round-8) kept; barrier added before it since
// the pipelined loop has no trailing sync.  XCD swizzle kept (FETCH 395->50MB).
// Requires gridDim.x % 8 == 0 and (gridDim.x/8) % stn == 0 (6144/2048 ok).
template <typename AT, typename OutT>
__global__ __launch_bounds__(256) void gemm_k192(
    const AT* __restrict__ A, int lda, int acol0,
    const ushort_t* __restrict__ BT, int bstride, int stn,
    const float* __restrict__ bias,
    OutT* __restrict__ Cout, int ldc)
{
    const int per = gridDim.x >> 3;
    const int bid = blockIdx.x;
    const int lb  = (bid & 7) * per + (bid >> 3);
    const int mt  = lb / stn;
    const int m0  = mt * 64;
    const int ns  = (lb - mt * stn) * 192;           // supertile column base
    const ushort_t* bt = BT + (bstride ? (size_t)(m0 >> 16) * (size_t)bstride : 0);

    __shared__ ushort_t SM[4 * 64 * 72];   // As | Bs0 | Bs1 | Bs2  (36,864 B)
    ushort_t* As = SM;

    const int t = threadIdx.x;
    const int wave = t >> 6, lane = t & 63;
    const int quad = lane >> 4, l15 = lane & 15;
    const int wm = (wave >> 1) * 32, wn = (wave & 1) * 32;
    const int srow = t >> 2, scol = (t & 3) * 16;

    const AT* ap = A + (size_t)(m0 + srow) * lda + acol0 + scol;
    const ushort_t* bp = bt + (size_t)(ns + srow) * 192 + scol;

    typename ARegT<AT>::T ra;
    uint4 rb[3][2];
    aload(ra, ap);                                   // k=0 loads in flight
#pragma unroll
    for (int nt = 0; nt < 3; ++nt) {
        const ushort_t* g = bp + nt * (64 * 192);
        rb[nt][0] = *(const uint4*)g;
        rb[nt][1] = *(const uint4*)(g + 8);
    }

    f32x4 acc[3][2][2] = {};

#pragma unroll
    for (int it = 0; it < 3; ++it) {
        const int kk = it * 64;
        if (it) __syncthreads();            // prev MFMA phase done; LDS free
        awrite(ra, &As[srow * 72 + scol]);  // vmcnt wait lands here (post-MFMA)
#pragma unroll
        for (int nt = 0; nt < 3; ++nt) {
            ushort_t* bs = SM + (nt + 1) * 4608;
            *(uint4*)&bs[srow * 72 + scol] = rb[nt][0];
            *(uint4*)&bs[srow * 72 + scol + 8] = rb[nt][1];
        }
        __syncthreads();
        if (it < 2) {                       // issue k+1 loads; first use = next awrite
            aload(ra, ap + kk + 64);
#pragma unroll
            for (int nt = 0; nt < 3; ++nt) {
                const ushort_t* g = bp + nt * (64 * 192) + kk + 64;
                rb[nt][0] = *(const uint4*)g;
                rb[nt][1] = *(const uint4*)(g + 8);
            }
        }
#pragma unroll
        for (int ks = 0; ks < 2; ks++) {
            short8 a0 = *(const short8*)&As[(wm + l15) * 72 + ks * 32 + quad * 8];
            short8 a1 = *(const short8*)&As[(wm + 16 + l15) * 72 + ks * 32 + quad * 8];
#pragma unroll
            for (int nt = 0; nt < 3; ++nt) {
                const ushort_t* bs = SM + (nt + 1) * 4608;
                short8 b0 = *(const short8*)&bs[(wn + l15) * 72 + ks * 32 + quad * 8];
                short8 b1 = *(const short8*)&bs[(wn + 16 + l15) * 72 + ks * 32 + quad * 8];
                acc[nt][0][0] = __builtin_amdgcn_mfma_f32_16x16x32_bf16(a0, b0, acc[nt][0][0], 0, 0, 0);
                acc[nt][0][1] = __builtin_amdgcn_mfma_f32_16x16x32_bf16(a0, b1, acc[nt][0][1], 0, 0, 0);
                acc[nt][1][0] = __builtin_amdgcn_mfma_f32_16x16x32_bf16(a1, b0, acc[nt][1][0], 0, 0, 0);
                acc[nt][1][1] = __builtin_amdgcn_mfma_f32_16x16x32_bf16(a1, b1, acc[nt][1][1], 0, 0, 0);
            }
        }
    }
    __syncthreads();    // quiesce LDS before epilogue reuse (loop has no trailing sync)

    // ---- LDS-transposed epilogue: wave-private region, no barriers needed.
    OutT* ew = (OutT*)SM + (size_t)wave * 32 * 40;
    const int erow = lane >> 1, ecol = (lane & 1) * 16;
    constexpr int EPC = 16 / (int)sizeof(OutT);   // elems per 16B chunk
    constexpr int NCH = 16 / EPC;                 // chunks per lane (2 or 4)
#pragma unroll
    for (int nt = 0; nt < 3; ++nt) {
        const int n0g = ns + nt * 64;
#pragma unroll
        for (int sm = 0; sm < 2; sm++)
#pragma unroll
            for (int sn = 0; sn < 2; sn++) {
                float bv = bias ? bias[n0g + wn + sn * 16 + l15] : 0.f;
#pragma unroll
                for (int r = 0; r < 4; r++)
                    storev(&ew[(sm * 16 + quad * 4 + r) * 40 + sn * 16 + l15],
                           acc[nt][sm][sn][r] + bv);
            }
        const OutT* er = ew + erow * 40 + ecol;
        OutT* gp = Cout + (size_t)(m0 + wm + erow) * ldc + n0g + wn + ecol;
#pragma unroll
        for (int h = 0; h < NCH; ++h)
            *(uint4*)(gp + h * EPC) = *(const uint4*)(er + h * EPC);
    }
}

// K2: 3x3 depthwise conv, SAME zero-pad, fp32 weights/bias, bf16 act in/out.
// Register-sliding, 4 channels/thread: each thread owns (b, x, c4) and a strip
// of 16 output rows.  Threads: 2*16*256*144 = 1,179,648 -> grid 4608 x 256.
#define R_STRIP 16

__global__ __launch_bounds__(256) void k2_dwconv(const ushort_t* __restrict__ qkv0,
        const float* __restrict__ wdw, const float* __restrict__ bdw,
        ushort_t* __restrict__ qkv1)
{
    const int tid = blockIdx.x * 256 + threadIdx.x;   // < 1,179,648
    const int c4 = tid % 144;
    const int t1 = tid / 144;                 // = (b*16 + s)*256 + x, < 8192
    const int x  = t1 & 255;
    const int t2 = t1 >> 8;
    const int s  = t2 & 15;
    const int b  = t2 >> 4;
    const int y0 = s * R_STRIP;
    const int cbase = c4 * 4;

    const bool xm = (x > 0), xp = (x < 255);
    const ushort_t* colbase = qkv0 + ((size_t)(b * HW_ + x) * C3_ + cbase);
    ushort_t*       ocol    = qkv1 + ((size_t)(b * HW_ + x) * C3_ + cbase);
    const size_t rstride = (size_t)256 * C3_;         // elems per image row

    // preload weights [ky][kx][4] and bias (coalesced float4 reads, L2-hot)
    float w[3][3][4], bw[4];
#pragma unroll
    for (int ky = 0; ky < 3; ++ky)
#pragma unroll
        for (int kx = 0; kx < 3; ++kx) {
            float4 wv = *(const float4*)(wdw + ((ky * 3 + kx) * C3_ + cbase));
            w[ky][kx][0] = wv.x; w[ky][kx][1] = wv.y; w[ky][kx][2] = wv.z; w[ky][kx][3] = wv.w;
        }
    {
        float4 bv = *(const float4*)(bdw + cbase);
        bw[0] = bv.x; bw[1] = bv.y; bw[2] = bv.z; bw[3] = bv.w;
    }

    const uint2 z2 = make_uint2(0, 0);
    auto loadrow = [&](int r, uint2& d0, uint2& d1, uint2& d2) {
        if ((unsigned)r <= 255u) {
            const ushort_t* p = colbase + (size_t)r * rstride;
            d1 = *(const uint2*)p;
            d0 = xm ? *(const uint2*)(p - C3_) : z2;
            d2 = xp ? *(const uint2*)(p + C3_) : z2;
        } else { d0 = z2; d1 = z2; d2 = z2; }
    };

    // acc role: output row o uses A[(o - y0 + 1) % 3]; at step RR (input row
    // r = y0-1+RR): prev-out(r-1) -> (RR+2)%3, cur-out(r) -> RR%3,
    // next-out(r+1) -> (RR+1)%3 — all compile-time after unroll.
    float A[3][4] = {};
    uint2 c0, c1, c2;
    loadrow(y0 - 1, c0, c1, c2);

#pragma unroll
    for (int RR = 0; RR < R_STRIP + 2; ++RR) {
        const int r = y0 - 1 + RR;
        uint2 n0 = z2, n1 = z2, n2 = z2;
        if (RR < R_STRIP + 1) loadrow(r + 1, n0, n1, n2);   // 1-step prefetch

        float rf[3][4];
        {
            const ushort_t* dd = (const ushort_t*)&c0;
#pragma unroll
            for (int j = 0; j < 4; ++j) rf[0][j] = b2f(dd[j]);
            dd = (const ushort_t*)&c1;
#pragma unroll
            for (int j = 0; j < 4; ++j) rf[1][j] = b2f(dd[j]);
            dd = (const ushort_t*)&c2;
#pragma unroll
            for (int j = 0; j < 4; ++j) rf[2][j] = b2f(dd[j]);
        }

        if (RR >= 1 && RR <= R_STRIP) {           // row r -> out r (ky=0 center)
#pragma unroll
            for (int kx = 0; kx < 3; ++kx)
#pragma unroll
                for (int j = 0; j < 4; ++j)
                    A[RR % 3][j] = fmaf(rf[kx][j], w[1][kx][j], A[RR % 3][j]);
        }
        if (RR <= R_STRIP - 1) {                  // row r -> out r+1 (ky=-1)
#pragma unroll
            for (int kx = 0; kx < 3; ++kx)
#pragma unroll
                for (int j = 0; j < 4; ++j)
                    A[(RR + 1) % 3][j] = fmaf(rf[kx][j], w[0][kx][j], A[(RR + 1) % 3][j]);
        }
        if (RR >= 2) {                            // row r -> out r-1 (ky=+1), emit r-1
#pragma unroll
            for (int kx = 0; kx < 3; ++kx)
#pragma unroll
                for (int j = 0; j < 4; ++j)
                    A[(RR + 2) % 3][j] = fmaf(rf[kx][j], w[2][kx][j], A[(RR + 2) % 3][j]);
            ushort_t ov[4];
#pragma unroll
            for (int j = 0; j < 4; ++j) {
                ov[j] = f2b(A[(RR + 2) % 3][j] + bw[j]);
                A[(RR + 2) % 3][j] = 0.f;
            }
            *(uint2*)(ocol + (size_t)(r - 1) * rstride) = *(uint2*)ov;
        }
        c0 = n0; c1 = n1; c2 = n2;
    }
}

// K3 (MFMA): per (b,head) 96x96 Gram of Z=[Q|K] over a 1024-row slice.
#define GR_LDSSTRIDE 136

__global__ __launch_bounds__(256) void k3_gram_mfma(const ushort_t* __restrict__ qkv1,
        float* __restrict__ P)
{
    const int bh = blockIdx.y;              // 0..7
    const int b = bh >> 2, h = bh & 3;
    const int slice = blockIdx.x;           // 0..63
    const int t = threadIdx.x;
    const int wave = t >> 6, lane = t & 63;
    const int quad = lane >> 4, l15 = lane & 15;

    __shared__ float red[7680];             // 30,720 B; low 26,112 B doubles as bf16 stage
    ushort_t* Z = (ushort_t*)red;

    f32x4 acc[15] = {};
    const ushort_t* basep = qkv1 + (size_t)(b * HW_) * C3_;
    const int row = t & 127;
    const int seghalf = t >> 7;             // 0: even segs, 1: odd segs

    for (int tile = 0; tile < 8; ++tile) {
        const int nbase = slice * 1024 + tile * 128;
        uint4 u[6];
#pragma unroll
        for (int k = 0; k < 6; ++k) {       // issue loads before barrier: overlap prev compute
            int seg = k * 2 + seghalf;      // 0..11; segs 0-5 = Q chans, 6-11 = K chans
            int cg = (seg < 6) ? (h * CH_ + seg * 8) : (C_ + h * CH_ + (seg - 6) * 8);
            u[k] = *(const uint4*)(basep + (size_t)(nbase + row) * C3_ + cg);
        }
        __syncthreads();                    // previous tile's compute done
#pragma unroll
        for (int k = 0; k < 6; ++k) {
            int seg = k * 2 + seghalf;
            int zc = seg * 8;               // z-channel base (Q:0-47, K:48-95)
            const ushort_t* dd = (const ushort_t*)&u[k];
#pragma unroll
            for (int j = 0; j < 8; ++j)
                Z[(zc + j) * GR_LDSSTRIDE + row] = dd[j];
        }
        __syncthreads();
        const int n0 = wave * 32 + quad * 8;
        short8 F[6];
#pragma unroll
        for (int c = 0; c < 6; ++c)
            F[c] = *(const short8*)&Z[(c * 16 + l15) * GR_LDSSTRIDE + n0];
#pragma unroll
        for (int i = 0; i < 3; ++i)
#pragma unroll
            for (int j = 0; j < 3; ++j)
                acc[i * 3 + j] = __builtin_amdgcn_mfma_f32_16x16x32_bf16(F[i], F[3 + j], acc[i * 3 + j], 0, 0, 0);
#pragma unroll
        for (int i = 0; i < 3; ++i) {
            acc[9 + i]  = __builtin_amdgcn_mfma_f32_16x16x32_bf16(F[i], F[i], acc[9 + i], 0, 0, 0);
            acc[12 + i] = __builtin_amdgcn_mfma_f32_16x16x32_bf16(F[3 + i], F[3 + i], acc[12 + i], 0, 0, 0);
        }
    }

    // pairwise cross-wave reduce: waves 1,3 -> LDS; waves 0,2 add and store
    __syncthreads();
    if (wave & 1) {
        float* dst = red + (wave >> 1) * (15 * 256);
#pragma unroll
        for (int tt = 0; tt < 15; ++tt)
            *(f32x4*)&dst[tt * 256 + lane * 4] = acc[tt];
    }
    __syncthreads();
    if (!(wave & 1)) {
        const float* src = red + (wave >> 1) * (15 * 256);
        const int sp = slice * 2 + (wave >> 1);     // 0..127
#pragma unroll
        for (int tt = 0; tt < 15; ++tt) {
            f32x4 v = *(const f32x4*)&src[tt * 256 + lane * 4];
#pragma unroll
            for (int r = 0; r < 4; ++r) {
                int e = (quad * 4 + r) * 16 + l15;  // row*16+col of the 16x16 tile
                P[(((size_t)bh * 15 + tt) * 128 + sp) * 256 + e] = acc[tt][r] + v[r];
            }
        }
    }
}

// K3r: sum the 128 per-slice partials; emit S (9 off-diag tiles), NQ/NK (diag tiles)
__global__ __launch_bounds__(256) void k3r_reduce(const float* __restrict__ P,
        float* __restrict__ S, float* __restrict__ NQ, float* __restrict__ NK)
{
    int idx = blockIdx.x * 256 + threadIdx.x;   // 8*15*256 = 30,720 exactly (120 blocks)
    int bh = idx / 3840;
    int rem = idx - bh * 3840;
    int tt = rem >> 8;
    int e = rem & 255;
    const float* p = P + (((size_t)bh * 15 + tt) * 128) * 256 + e;
    float s = 0.f;
#pragma unroll 8
    for (int sp = 0; sp < 128; ++sp) s += p[(size_t)sp * 256];
    int r = e >> 4, c = e & 15;
    if (tt < 9) {
        int i = tt / 3, j = tt - i * 3;
        S[bh * 2304 + (i * 16 + r) * 48 + j * 16 + c] = s;
    } else if (tt < 12) {
        if (r == c) NQ[bh * 48 + (tt - 9) * 16 + r] = s;
    } else {
        if (r == c) NK[bh * 48 + (tt - 12) * 16 + r] = s;
    }
}

// K4a: attn = softmax_row( S * temp / (|q||k|) ), one 64-thread block per (bh,cq) row
__global__ void k4a_softmax(const float* __restrict__ S, const float* __restrict__ NQ,
                            const float* __restrict__ NK, const float* __restrict__ temp,
                            float* __restrict__ ATT)
{
    int bh = blockIdx.y, cq = blockIdx.x;
    int h = bh & 3;
    int t = threadIdx.x;
    float nq = fmaxf(sqrtf(NQ[bh * 48 + cq]), 1e-12f);
    float tv = temp[h];
    float logit = -1e30f;
    if (t < 48) {
        float nk = fmaxf(sqrtf(NK[bh * 48 + t]), 1e-12f);
        logit = S[bh * 2304 + cq * 48 + t] * tv / (nq * nk);
    }
    float m = logit;
    for (int o = 32; o > 0; o >>= 1) m = fmaxf(m, __shfl_xor(m, o));
    float e = (t < 48) ? __expf(logit - m) : 0.f;
    float ssum = e;
    for (int o = 32; o > 0; o >>= 1) ssum += __shfl_xor(ssum, o);
    if (t < 48) ATT[bh * 2304 + cq * 48 + t] = e / ssum;
}

// K4b: fuse attention-apply + output projection into one per-batch 192x192 matrix,
// stored TRANSPOSED so the final GEMM's B-operand reads contiguous K.
__global__ void k4b_buildM(const float* __restrict__ ATT, const float* __restrict__ wout,
                           ushort_t* __restrict__ MT)
{
    int idx = blockIdx.x * 256 + threadIdx.x;      // 2*192*192 = 73728 exactly
    int b = idx / 36864; int rem = idx - b * 36864;
    int j = rem / 192;   int d = rem - j * 192;
    int h = d / 48, dd = d - h * 48;
    const float* ap = ATT + (size_t)(b * 4 + h) * 2304 + dd;   // stride 48 over cq
    const float* wp = wout + (size_t)(h * 48) * 192 + j;       // stride 192 over cq
    float s = 0.f;
#pragma unroll 8
    for (int cq = 0; cq < 48; cq++) s += ap[cq * 48] * wp[cq * 192];
    MT[idx] = f2b(s);
}

extern "C" void kernel_launch(void* const* d_in, const int* in_sizes, int n_in,
                              void* d_out, int out_size, void* d_ws, size_t ws_size,
                              hipStream_t stream) {
    const float* x     = (const float*)d_in[0];
    const float* w_qkv = (const float*)d_in[1];
    const float* b_qkv = (const float*)d_in[2];
    const float* w_dw  = (const float*)d_in[3];
    const float* b_dw  = (const float*)d_in[4];
    const float* temp  = (const float*)d_in[5];
    const float* w_out = (const float*)d_in[6];
    const float* b_out = (const float*)d_in[7];
    float* out = (float*)d_out;

    char* ws = (char*)d_ws;
    ushort_t* qkv0 = (ushort_t*)(ws + OFF_QKV0);
    ushort_t* qkv1 = (ushort_t*)(ws + OFF_QKV1);
    float*    Pb   = (float*)(ws + OFF_P);
    ushort_t* btq  = (ushort_t*)(ws + OFF_BT);
    float*    Sb   = (float*)(ws + OFF_S);
    float*    NQ   = (float*)(ws + OFF_NQ);
    float*    NK   = (float*)(ws + OFF_NK);
    float*    ATT  = (float*)(ws + OFF_ATTN);
    ushort_t* MT   = (ushort_t*)(ws + OFF_MT);

    k0_transpose<<<432, 256, 0, stream>>>(w_qkv, btq);
    // qkv0 = x @ w_qkv + b_qkv  (fp32 A converted in staging; XCD-swizzled 1-D grid:
    // 2048 m-tiles * 3 supertiles (192 cols each) = 6144 blocks)
    gemm_k192<float, ushort_t><<<6144, 256, 0, stream>>>(x, 192, 0, btq, 0, 3, b_qkv, qkv0, 576);
    // qkv1 = depthwise3x3(qkv0) + b_dw   (2*16*256*144 threads / 256 = 4608 blocks)
    k2_dwconv<<<4608, 256, 0, stream>>>(qkv0, w_dw, b_dw, qkv1);
    // MFMA Gram partials (P aliases dead qkv0), then reduce -> S, NQ, NK
    k3_gram_mfma<<<dim3(64, 8), 256, 0, stream>>>(qkv1, Pb);
    k3r_reduce<<<120, 256, 0, stream>>>(Pb, Sb, NQ, NK);
    // softmax(normalized, temperature-scaled)
    k4a_softmax<<<dim3(48, 8), 64, 0, stream>>>(Sb, NQ, NK, temp, ATT);
    // fused (blockdiag attn)^T @ Wout, transposed for the GEMM
    k4b_buildM<<<288, 256, 0, stream>>>(ATT, w_out, MT);
    // out = v @ M_b + b_out   (2048 m-tiles * 1 supertile = 2048 blocks)
    gemm_k192<ushort_t, float><<<2048, 256, 0, stream>>>(qkv1, 576, 384, MT, 36864, 1, b_out, out, 192);
}

// Round 10
// 437.261 us; speedup vs baseline: 1.3493x; 1.3493x over previous
//
#include <hip/hip_runtime.h>

typedef unsigned short ushort_t;
typedef __attribute__((ext_vector_type(8))) short short8;
typedef __attribute__((ext_vector_type(4))) float f32x4;

#define B_ 2
#define HW_ 65536          // 256*256 per batch
#define MTOT_ 131072       // B*H*W rows
#define C_ 192
#define C3_ 576
#define HEADS_ 4
#define CH_ 48

// ---- workspace layout (bytes), total ~302.5 MB ----
#define OFF_QKV0  ((size_t)0)                       // bf16 131072*576*2 = 150,994,944
#define OFF_QKV1  ((size_t)150994944)               // bf16, same size
#define OFF_P     OFF_QKV0                          // gram partials (15.7 MB) alias qkv0: dead after dwconv
#define OFF_BT    ((size_t)301989888)               // w_qkv^T bf16 576*192*2 = 221,184
#define OFF_S     ((size_t)302211072)               // fp32 8*48*48 = 73,728 B
#define OFF_NQ    ((size_t)302284800)               // fp32 8*48 = 1,536 B
#define OFF_NK    ((size_t)302286336)               // fp32 8*48 = 1,536 B
#define OFF_ATTN  ((size_t)302287872)               // fp32 8*48*48 = 73,728 B
#define OFF_MT    ((size_t)302361600)               // bf16 2*192*192 = 147,456 B

__device__ __forceinline__ float b2f(ushort_t u) {
    unsigned v = ((unsigned)u) << 16;
    return __builtin_bit_cast(float, v);
}
__device__ __forceinline__ ushort_t f2b(float f) {
    unsigned u = __builtin_bit_cast(unsigned, f);
    u = (u + 0x7fffu + ((u >> 16) & 1u)) >> 16;   // RNE
    return (ushort_t)u;
}
__device__ __forceinline__ void storev(float* p, float v) { *p = v; }
__device__ __forceinline__ void storev(ushort_t* p, float v) { *p = f2b(v); }

// K0: transpose+convert w_qkv fp32 [192,576] -> bf16 [576,192]
__global__ void k0_transpose(const float* __restrict__ w, ushort_t* __restrict__ bt) {
    int idx = blockIdx.x * 256 + threadIdx.x;        // 576*192 = 110592 exactly
    int n = idx / 192, k = idx - n * 192;
    bt[idx] = f2b(w[k * 576 + n]);
}

// MFMA GEMM: C[M,N] = A[M,192] * BT[N,192]^T(bf16) + bias(fp32).  A fp32 (converted
// during LDS write) or bf16.  64x192 C supertile/block (3 n-tiles), BK=64.
// ROUND-10: register-staged pipeline, SPILL-PROOF CODEGEN.  Round-9's struct+
// helper-function staging was demoted to scratch (VGPR 72->60, WRITE_SIZE
// 147->585MB = scratch round-trips, dur 117->229us).  Same schedule, but all
// staging lives in NAMED scalar registers (af0..af3 / au0,au1 / b0l..b2h),
// three iterations written straight-line via macros — no barrier-crossing
// aggregates, no function boundaries.  Per iteration:
//   STAGE (vmcnt wait lands here, AFTER prev MFMA phase) -> barrier ->
//   issue next loads -> MFMA -> barrier
// LDS-transposed wide epilogue (round-8) kept.  XCD swizzle kept.
// Requires gridDim.x % 8 == 0 and (gridDim.x/8) % stn == 0 (6144/2048 ok).
template <typename AT, typename OutT>
__global__ __launch_bounds__(256) void gemm_k192(
    const AT* __restrict__ A, int lda, int acol0,
    const ushort_t* __restrict__ BT, int bstride, int stn,
    const float* __restrict__ bias,
    OutT* __restrict__ Cout, int ldc)
{
    const int per = gridDim.x >> 3;
    const int bid = blockIdx.x;
    const int lb  = (bid & 7) * per + (bid >> 3);
    const int mt  = lb / stn;
    const int m0  = mt * 64;
    const int ns  = (lb - mt * stn) * 192;           // supertile column base
    const ushort_t* bt = BT + (bstride ? (size_t)(m0 >> 16) * (size_t)bstride : 0);

    __shared__ ushort_t SM[4 * 64 * 72];   // As | Bs0 | Bs1 | Bs2  (36,864 B)
    ushort_t* As = SM;

    const int t = threadIdx.x;
    const int wave = t >> 6, lane = t & 63;
    const int quad = lane >> 4, l15 = lane & 15;
    const int wm = (wave >> 1) * 32, wn = (wave & 1) * 32;
    const int srow = t >> 2, scol = (t & 3) * 16;

    const AT* ap = A + (size_t)(m0 + srow) * lda + acol0 + scol;
    const ushort_t* bp0 = bt + (size_t)(ns + srow) * 192 + scol;
    const ushort_t* bp1 = bp0 + 64 * 192;
    const ushort_t* bp2 = bp1 + 64 * 192;
    ushort_t* awp  = &As[srow * 72 + scol];
    ushort_t* bwp0 = SM + 1 * 4608 + srow * 72 + scol;
    ushort_t* bwp1 = SM + 2 * 4608 + srow * 72 + scol;
    ushort_t* bwp2 = SM + 3 * 4608 + srow * 72 + scol;

    // named staging registers — single set, reused every iteration
    float4 af0, af1, af2, af3;     // fp32-A path
    uint4  au0, au1;               // bf16-A path
    uint4  b0l, b0h, b1l, b1h, b2l, b2h;

#define GLOADS(KK)                                                     \
    if constexpr (sizeof(AT) == 4) {                                   \
        af0 = *(const float4*)((const float*)(ap) + (KK));             \
        af1 = *(const float4*)((const float*)(ap) + (KK) + 4);         \
        af2 = *(const float4*)((const float*)(ap) + (KK) + 8);         \
        af3 = *(const float4*)((const float*)(ap) + (KK) + 12);       \
    } else {                                                           \
        au0 = *(const uint4*)((const ushort_t*)(ap) + (KK));           \
        au1 = *(const uint4*)((const ushort_t*)(ap) + (KK) + 8);       \
    }                                                                  \
    b0l = *(const uint4*)(bp0 + (KK)); b0h = *(const uint4*)(bp0 + (KK) + 8); \
    b1l = *(const uint4*)(bp1 + (KK)); b1h = *(const uint4*)(bp1 + (KK) + 8); \
    b2l = *(const uint4*)(bp2 + (KK)); b2h = *(const uint4*)(bp2 + (KK) + 8);

#define STAGE()                                                        \
    if constexpr (sizeof(AT) == 4) {                                   \
        ushort_t o[16];                                                \
        o[0]=f2b(af0.x); o[1]=f2b(af0.y); o[2]=f2b(af0.z); o[3]=f2b(af0.w);     \
        o[4]=f2b(af1.x); o[5]=f2b(af1.y); o[6]=f2b(af1.z); o[7]=f2b(af1.w);     \
        o[8]=f2b(af2.x); o[9]=f2b(af2.y); o[10]=f2b(af2.z); o[11]=f2b(af2.w);   \
        o[12]=f2b(af3.x); o[13]=f2b(af3.y); o[14]=f2b(af3.z); o[15]=f2b(af3.w); \
        *(uint4*)awp = *(uint4*)o; *(uint4*)(awp + 8) = *(uint4*)(o + 8);       \
    } else {                                                           \
        *(uint4*)awp = au0; *(uint4*)(awp + 8) = au1;                  \
    }                                                                  \
    *(uint4*)bwp0 = b0l; *(uint4*)(bwp0 + 8) = b0h;                    \
    *(uint4*)bwp1 = b1l; *(uint4*)(bwp1 + 8) = b1h;                    \
    *(uint4*)bwp2 = b2l; *(uint4*)(bwp2 + 8) = b2h;

#define MFMA_PHASE()                                                   \
    _Pragma("unroll")                                                  \
    for (int ks = 0; ks < 2; ks++) {                                   \
        short8 a0 = *(const short8*)&As[(wm + l15) * 72 + ks * 32 + quad * 8];      \
        short8 a1 = *(const short8*)&As[(wm + 16 + l15) * 72 + ks * 32 + quad * 8]; \
        _Pragma("unroll")                                              \
        for (int nt = 0; nt < 3; ++nt) {                               \
            const ushort_t* bs = SM + (nt + 1) * 4608;                 \
            short8 b0 = *(const short8*)&bs[(wn + l15) * 72 + ks * 32 + quad * 8];      \
            short8 b1 = *(const short8*)&bs[(wn + 16 + l15) * 72 + ks * 32 + quad * 8]; \
            acc[nt][0][0] = __builtin_amdgcn_mfma_f32_16x16x32_bf16(a0, b0, acc[nt][0][0], 0, 0, 0); \
            acc[nt][0][1] = __builtin_amdgcn_mfma_f32_16x16x32_bf16(a0, b1, acc[nt][0][1], 0, 0, 0); \
            acc[nt][1][0] = __builtin_amdgcn_mfma_f32_16x16x32_bf16(a1, b0, acc[nt][1][0], 0, 0, 0); \
            acc[nt][1][1] = __builtin_amdgcn_mfma_f32_16x16x32_bf16(a1, b1, acc[nt][1][1], 0, 0, 0); \
        }                                                              \
    }

    f32x4 acc[3][2][2] = {};

    GLOADS(0);                    // k=0 loads in flight
    // ---- iter 0 ----
    STAGE();                      // vmcnt wait here (nothing to overlap yet)
    __syncthreads();
    GLOADS(64);                   // k=1 loads fly under iter-0 MFMAs
    MFMA_PHASE();
    __syncthreads();
    // ---- iter 1 ----
    STAGE();                      // waits k=1 loads — after iter-0 MFMA phase
    __syncthreads();
    GLOADS(128);                  // k=2 loads fly under iter-1 MFMAs
    MFMA_PHASE();
    __syncthreads();
    // ---- iter 2 ----
    STAGE();                      // waits k=2 loads — after iter-1 MFMA phase
    __syncthreads();
    MFMA_PHASE();
    __syncthreads();              // quiesce LDS before epilogue reuse

#undef GLOADS
#undef STAGE
#undef MFMA_PHASE

    // ---- LDS-transposed epilogue: wave-private region, no barriers needed.
    OutT* ew = (OutT*)SM + (size_t)wave * 32 * 40;
    const int erow = lane >> 1, ecol = (lane & 1) * 16;
    constexpr int EPC = 16 / (int)sizeof(OutT);   // elems per 16B chunk
    constexpr int NCH = 16 / EPC;                 // chunks per lane (2 or 4)
#pragma unroll
    for (int nt = 0; nt < 3; ++nt) {
        const int n0g = ns + nt * 64;
#pragma unroll
        for (int sm = 0; sm < 2; sm++)
#pragma unroll
            for (int sn = 0; sn < 2; sn++) {
                float bv = bias ? bias[n0g + wn + sn * 16 + l15] : 0.f;
#pragma unroll
                for (int r = 0; r < 4; r++)
                    storev(&ew[(sm * 16 + quad * 4 + r) * 40 + sn * 16 + l15],
                           acc[nt][sm][sn][r] + bv);
            }
        const OutT* er = ew + erow * 40 + ecol;
        OutT* gp = Cout + (size_t)(m0 + wm + erow) * ldc + n0g + wn + ecol;
#pragma unroll
        for (int h = 0; h < NCH; ++h)
            *(uint4*)(gp + h * EPC) = *(const uint4*)(er + h * EPC);
    }
}

// K2: 3x3 depthwise conv, SAME zero-pad, fp32 weights/bias, bf16 act in/out.
// Register-sliding, 4 channels/thread: each thread owns (b, x, c4) and a strip
// of 16 output rows.  Threads: 2*16*256*144 = 1,179,648 -> grid 4608 x 256.
#define R_STRIP 16

__global__ __launch_bounds__(256) void k2_dwconv(const ushort_t* __restrict__ qkv0,
        const float* __restrict__ wdw, const float* __restrict__ bdw,
        ushort_t* __restrict__ qkv1)
{
    const int tid = blockIdx.x * 256 + threadIdx.x;   // < 1,179,648
    const int c4 = tid % 144;
    const int t1 = tid / 144;                 // = (b*16 + s)*256 + x, < 8192
    const int x  = t1 & 255;
    const int t2 = t1 >> 8;
    const int s  = t2 & 15;
    const int b  = t2 >> 4;
    const int y0 = s * R_STRIP;
    const int cbase = c4 * 4;

    const bool xm = (x > 0), xp = (x < 255);
    const ushort_t* colbase = qkv0 + ((size_t)(b * HW_ + x) * C3_ + cbase);
    ushort_t*       ocol    = qkv1 + ((size_t)(b * HW_ + x) * C3_ + cbase);
    const size_t rstride = (size_t)256 * C3_;         // elems per image row

    // preload weights [ky][kx][4] and bias (coalesced float4 reads, L2-hot)
    float w[3][3][4], bw[4];
#pragma unroll
    for (int ky = 0; ky < 3; ++ky)
#pragma unroll
        for (int kx = 0; kx < 3; ++kx) {
            float4 wv = *(const float4*)(wdw + ((ky * 3 + kx) * C3_ + cbase));
            w[ky][kx][0] = wv.x; w[ky][kx][1] = wv.y; w[ky][kx][2] = wv.z; w[ky][kx][3] = wv.w;
        }
    {
        float4 bv = *(const float4*)(bdw + cbase);
        bw[0] = bv.x; bw[1] = bv.y; bw[2] = bv.z; bw[3] = bv.w;
    }

    const uint2 z2 = make_uint2(0, 0);
    auto loadrow = [&](int r, uint2& d0, uint2& d1, uint2& d2) {
        if ((unsigned)r <= 255u) {
            const ushort_t* p = colbase + (size_t)r * rstride;
            d1 = *(const uint2*)p;
            d0 = xm ? *(const uint2*)(p - C3_) : z2;
            d2 = xp ? *(const uint2*)(p + C3_) : z2;
        } else { d0 = z2; d1 = z2; d2 = z2; }
    };

    // acc role: output row o uses A[(o - y0 + 1) % 3]; at step RR (input row
    // r = y0-1+RR): prev-out(r-1) -> (RR+2)%3, cur-out(r) -> RR%3,
    // next-out(r+1) -> (RR+1)%3 — all compile-time after unroll.
    float A[3][4] = {};
    uint2 c0, c1, c2;
    loadrow(y0 - 1, c0, c1, c2);

#pragma unroll
    for (int RR = 0; RR < R_STRIP + 2; ++RR) {
        const int r = y0 - 1 + RR;
        uint2 n0 = z2, n1 = z2, n2 = z2;
        if (RR < R_STRIP + 1) loadrow(r + 1, n0, n1, n2);   // 1-step prefetch

        float rf[3][4];
        {
            const ushort_t* dd = (const ushort_t*)&c0;
#pragma unroll
            for (int j = 0; j < 4; ++j) rf[0][j] = b2f(dd[j]);
            dd = (const ushort_t*)&c1;
#pragma unroll
            for (int j = 0; j < 4; ++j) rf[1][j] = b2f(dd[j]);
            dd = (const ushort_t*)&c2;
#pragma unroll
            for (int j = 0; j < 4; ++j) rf[2][j] = b2f(dd[j]);
        }

        if (RR >= 1 && RR <= R_STRIP) {           // row r -> out r (ky=0 center)
#pragma unroll
            for (int kx = 0; kx < 3; ++kx)
#pragma unroll
                for (int j = 0; j < 4; ++j)
                    A[RR % 3][j] = fmaf(rf[kx][j], w[1][kx][j], A[RR % 3][j]);
        }
        if (RR <= R_STRIP - 1) {                  // row r -> out r+1 (ky=-1)
#pragma unroll
            for (int kx = 0; kx < 3; ++kx)
#pragma unroll
                for (int j = 0; j < 4; ++j)
                    A[(RR + 1) % 3][j] = fmaf(rf[kx][j], w[0][kx][j], A[(RR + 1) % 3][j]);
        }
        if (RR >= 2) {                            // row r -> out r-1 (ky=+1), emit r-1
#pragma unroll
            for (int kx = 0; kx < 3; ++kx)
#pragma unroll
                for (int j = 0; j < 4; ++j)
                    A[(RR + 2) % 3][j] = fmaf(rf[kx][j], w[2][kx][j], A[(RR + 2) % 3][j]);
            ushort_t ov[4];
#pragma unroll
            for (int j = 0; j < 4; ++j) {
                ov[j] = f2b(A[(RR + 2) % 3][j] + bw[j]);
                A[(RR + 2) % 3][j] = 0.f;
            }
            *(uint2*)(ocol + (size_t)(r - 1) * rstride) = *(uint2*)ov;
        }
        c0 = n0; c1 = n1; c2 = n2;
    }
}

// K3 (MFMA): per (b,head) 96x96 Gram of Z=[Q|K] over a 1024-row slice.
#define GR_LDSSTRIDE 136

__global__ __launch_bounds__(256) void k3_gram_mfma(const ushort_t* __restrict__ qkv1,
        float* __restrict__ P)
{
    const int bh = blockIdx.y;              // 0..7
    const int b = bh >> 2, h = bh & 3;
    const int slice = blockIdx.x;           // 0..63
    const int t = threadIdx.x;
    const int wave = t >> 6, lane = t & 63;
    const int quad = lane >> 4, l15 = lane & 15;

    __shared__ float red[7680];             // 30,720 B; low 26,112 B doubles as bf16 stage
    ushort_t* Z = (ushort_t*)red;

    f32x4 acc[15] = {};
    const ushort_t* basep = qkv1 + (size_t)(b * HW_) * C3_;
    const int row = t & 127;
    const int seghalf = t >> 7;             // 0: even segs, 1: odd segs

    for (int tile = 0; tile < 8; ++tile) {
        const int nbase = slice * 1024 + tile * 128;
        uint4 u[6];
#pragma unroll
        for (int k = 0; k < 6; ++k) {       // issue loads before barrier: overlap prev compute
            int seg = k * 2 + seghalf;      // 0..11; segs 0-5 = Q chans, 6-11 = K chans
            int cg = (seg < 6) ? (h * CH_ + seg * 8) : (C_ + h * CH_ + (seg - 6) * 8);
            u[k] = *(const uint4*)(basep + (size_t)(nbase + row) * C3_ + cg);
        }
        __syncthreads();                    // previous tile's compute done
#pragma unroll
        for (int k = 0; k < 6; ++k) {
            int seg = k * 2 + seghalf;
            int zc = seg * 8;               // z-channel base (Q:0-47, K:48-95)
            const ushort_t* dd = (const ushort_t*)&u[k];
#pragma unroll
            for (int j = 0; j < 8; ++j)
                Z[(zc + j) * GR_LDSSTRIDE + row] = dd[j];
        }
        __syncthreads();
        const int n0 = wave * 32 + quad * 8;
        short8 F[6];
#pragma unroll
        for (int c = 0; c < 6; ++c)
            F[c] = *(const short8*)&Z[(c * 16 + l15) * GR_LDSSTRIDE + n0];
#pragma unroll
        for (int i = 0; i < 3; ++i)
#pragma unroll
            for (int j = 0; j < 3; ++j)
                acc[i * 3 + j] = __builtin_amdgcn_mfma_f32_16x16x32_bf16(F[i], F[3 + j], acc[i * 3 + j], 0, 0, 0);
#pragma unroll
        for (int i = 0; i < 3; ++i) {
            acc[9 + i]  = __builtin_amdgcn_mfma_f32_16x16x32_bf16(F[i], F[i], acc[9 + i], 0, 0, 0);
            acc[12 + i] = __builtin_amdgcn_mfma_f32_16x16x32_bf16(F[3 + i], F[3 + i], acc[12 + i], 0, 0, 0);
        }
    }

    // pairwise cross-wave reduce: waves 1,3 -> LDS; waves 0,2 add and store
    __syncthreads();
    if (wave & 1) {
        float* dst = red + (wave >> 1) * (15 * 256);
#pragma unroll
        for (int tt = 0; tt < 15; ++tt)
            *(f32x4*)&dst[tt * 256 + lane * 4] = acc[tt];
    }
    __syncthreads();
    if (!(wave & 1)) {
        const float* src = red + (wave >> 1) * (15 * 256);
        const int sp = slice * 2 + (wave >> 1);     // 0..127
#pragma unroll
        for (int tt = 0; tt < 15; ++tt) {
            f32x4 v = *(const f32x4*)&src[tt * 256 + lane * 4];
#pragma unroll
            for (int r = 0; r < 4; ++r) {
                int e = (quad * 4 + r) * 16 + l15;  // row*16+col of the 16x16 tile
                P[(((size_t)bh * 15 + tt) * 128 + sp) * 256 + e] = acc[tt][r] + v[r];
            }
        }
    }
}

// K3r: sum the 128 per-slice partials; emit S (9 off-diag tiles), NQ/NK (diag tiles)
__global__ __launch_bounds__(256) void k3r_reduce(const float* __restrict__ P,
        float* __restrict__ S, float* __restrict__ NQ, float* __restrict__ NK)
{
    int idx = blockIdx.x * 256 + threadIdx.x;   // 8*15*256 = 30,720 exactly (120 blocks)
    int bh = idx / 3840;
    int rem = idx - bh * 3840;
    int tt = rem >> 8;
    int e = rem & 255;
    const float* p = P + (((size_t)bh * 15 + tt) * 128) * 256 + e;
    float s = 0.f;
#pragma unroll 8
    for (int sp = 0; sp < 128; ++sp) s += p[(size_t)sp * 256];
    int r = e >> 4, c = e & 15;
    if (tt < 9) {
        int i = tt / 3, j = tt - i * 3;
        S[bh * 2304 + (i * 16 + r) * 48 + j * 16 + c] = s;
    } else if (tt < 12) {
        if (r == c) NQ[bh * 48 + (tt - 9) * 16 + r] = s;
    } else {
        if (r == c) NK[bh * 48 + (tt - 12) * 16 + r] = s;
    }
}

// K4a: attn = softmax_row( S * temp / (|q||k|) ), one 64-thread block per (bh,cq) row
__global__ void k4a_softmax(const float* __restrict__ S, const float* __restrict__ NQ,
                            const float* __restrict__ NK, const float* __restrict__ temp,
                            float* __restrict__ ATT)
{
    int bh = blockIdx.y, cq = blockIdx.x;
    int h = bh & 3;
    int t = threadIdx.x;
    float nq = fmaxf(sqrtf(NQ[bh * 48 + cq]), 1e-12f);
    float tv = temp[h];
    float logit = -1e30f;
    if (t < 48) {
        float nk = fmaxf(sqrtf(NK[bh * 48 + t]), 1e-12f);
        logit = S[bh * 2304 + cq * 48 + t] * tv / (nq * nk);
    }
    float m = logit;
    for (int o = 32; o > 0; o >>= 1) m = fmaxf(m, __shfl_xor(m, o));
    float e = (t < 48) ? __expf(logit - m) : 0.f;
    float ssum = e;
    for (int o = 32; o > 0; o >>= 1) ssum += __shfl_xor(ssum, o);
    if (t < 48) ATT[bh * 2304 + cq * 48 + t] = e / ssum;
}

// K4b: fuse attention-apply + output projection into one per-batch 192x192 matrix,
// stored TRANSPOSED so the final GEMM's B-operand reads contiguous K.
__global__ void k4b_buildM(const float* __restrict__ ATT, const float* __restrict__ wout,
                           ushort_t* __restrict__ MT)
{
    int idx = blockIdx.x * 256 + threadIdx.x;      // 2*192*192 = 73728 exactly
    int b = idx / 36864; int rem = idx - b * 36864;
    int j = rem / 192;   int d = rem - j * 192;
    int h = d / 48, dd = d - h * 48;
    const float* ap = ATT + (size_t)(b * 4 + h) * 2304 + dd;   // stride 48 over cq
    const float* wp = wout + (size_t)(h * 48) * 192 + j;       // stride 192 over cq
    float s = 0.f;
#pragma unroll 8
    for (int cq = 0; cq < 48; cq++) s += ap[cq * 48] * wp[cq * 192];
    MT[idx] = f2b(s);
}

extern "C" void kernel_launch(void* const* d_in, const int* in_sizes, int n_in,
                              void* d_out, int out_size, void* d_ws, size_t ws_size,
                              hipStream_t stream) {
    const float* x     = (const float*)d_in[0];
    const float* w_qkv = (const float*)d_in[1];
    const float* b_qkv = (const float*)d_in[2];
    const float* w_dw  = (const float*)d_in[3];
    const float* b_dw  = (const float*)d_in[4];
    const float* temp  = (const float*)d_in[5];
    const float* w_out = (const float*)d_in[6];
    const float* b_out = (const float*)d_in[7];
    float* out = (float*)d_out;

    char* ws = (char*)d_ws;
    ushort_t* qkv0 = (ushort_t*)(ws + OFF_QKV0);
    ushort_t* qkv1 = (ushort_t*)(ws + OFF_QKV1);
    float*    Pb   = (float*)(ws + OFF_P);
    ushort_t* btq  = (ushort_t*)(ws + OFF_BT);
    float*    Sb   = (float*)(ws + OFF_S);
    float*    NQ   = (float*)(ws + OFF_NQ);
    float*    NK   = (float*)(ws + OFF_NK);
    float*    ATT  = (float*)(ws + OFF_ATTN);
    ushort_t* MT   = (ushort_t*)(ws + OFF_MT);

    k0_transpose<<<432, 256, 0, stream>>>(w_qkv, btq);
    // qkv0 = x @ w_qkv + b_qkv  (fp32 A converted in staging; XCD-swizzled 1-D grid:
    // 2048 m-tiles * 3 supertiles (192 cols each) = 6144 blocks)
    gemm_k192<float, ushort_t><<<6144, 256, 0, stream>>>(x, 192, 0, btq, 0, 3, b_qkv, qkv0, 576);
    // qkv1 = depthwise3x3(qkv0) + b_dw   (2*16*256*144 threads / 256 = 4608 blocks)
    k2_dwconv<<<4608, 256, 0, stream>>>(qkv0, w_dw, b_dw, qkv1);
    // MFMA Gram partials (P aliases dead qkv0), then reduce -> S, NQ, NK
    k3_gram_mfma<<<dim3(64, 8), 256, 0, stream>>>(qkv1, Pb);
    k3r_reduce<<<120, 256, 0, stream>>>(Pb, Sb, NQ, NK);
    // softmax(normalized, temperature-scaled)
    k4a_softmax<<<dim3(48, 8), 64, 0, stream>>>(Sb, NQ, NK, temp, ATT);
    // fused (blockdiag attn)^T @ Wout, transposed for the GEMM
    k4b_buildM<<<288, 256, 0, stream>>>(ATT, w_out, MT);
    // out = v @ M_b + b_out   (2048 m-tiles * 1 supertile = 2048 blocks)
    gemm_k192<ushort_t, float><<<2048, 256, 0, stream>>>(qkv1, 576, 384, MT, 36864, 1, b_out, out, 192);
}